// Round 8
// baseline (418.733 us; speedup 1.0000x reference)
//
#include <hip/hip_runtime.h>

#define M_DIM 8192
#define IN_DIM 4096
#define OUT_DIM 4096

typedef int   v4i  __attribute__((ext_vector_type(4)));
typedef int   v16i __attribute__((ext_vector_type(16)));
typedef short v8s  __attribute__((ext_vector_type(8)));
typedef float v4f  __attribute__((ext_vector_type(4)));
typedef float v16f __attribute__((ext_vector_type(16)));

static __device__ __forceinline__ int pack4(int a, int b, int c, int d) {
    return (a & 255) | ((b & 255) << 8) | ((c & 255) << 16) | ((d & 255) << 24);
}

static __device__ __forceinline__ short f2bf(float f) {  // RNE
    unsigned u = __float_as_uint(f);
    u = (u + 0x7FFFu + ((u >> 16) & 1u)) >> 16;
    return (short)u;
}

static __device__ __forceinline__ short i2bf(int v) {  // exact for |v| <= 128
    float f = (float)v;
    return (short)(__float_as_uint(f) >> 16);
}

static __device__ __forceinline__ float gelu_tanh(float u) {
    float u2 = u * u;
    float p  = fmaf(u2, 0.0356774081f, 0.7978845608f);
    float v  = u * p;
    float e  = __builtin_amdgcn_exp2f(v * 2.8853900818f);
    return u - u * __builtin_amdgcn_rcpf(e + 1.0f);
}

static __device__ __forceinline__ void async_cp16(const signed char* g, signed char* l) {
    __builtin_amdgcn_global_load_lds((const __attribute__((address_space(1))) void*)g,
                                     (__attribute__((address_space(3))) void*)l, 16, 0, 0);
}

// Tiled operand layout (shared by pack paths and GEMM staging):
//   buf[((tile*64 + kk)*16 + gp)*1024 + lane*16 + j] = src[row][k]
//   row = tile*256 + (gp>>1)*32 + (lane&31)
//   k   = kk*64 + (gp&1)*32 + (lane>>5)*16 + j ,  j in [0,16)

// ---------------- zero T (atomic accumulator init) ----------------
__global__ __launch_bounds__(256) void zero_t_kernel(float* __restrict__ T) {
    const int flat = blockIdx.x * 256 + threadIdx.x;  // 16384 threads x 8 = 131072 = M*R
    float4 z = {0.f, 0.f, 0.f, 0.f};
    float4* tz = (float4*)(T + (size_t)flat * 8);
    tz[0] = z; tz[1] = z;
}

// ---------------- fused pack: x-path + w-path in ONE kernel ----------------
// blocks [0,2048): x int32 -> int8 tiled AND T[m][r] += sum_k x[m][k]*A[r][k]
//   (4-way K-split; lora_a is converted f32->bf16 INLINE — la is 256KB,
//    L2-resident, so no a16 staging pass and no serial dependency).
// blocks [2048,6144): weight int32 -> int8 tiled (gather).
// Mixing both paths in one grid lets the BW-bound w-blocks fill the
// x-blocks' latency stalls, and makes the pack side ONE dispatch whose
// counters are visible in the top-5 table.
__global__ __launch_bounds__(256) void pack_all_kernel(const int* __restrict__ x,
                                                       const float* __restrict__ la,
                                                       signed char* __restrict__ x8t,
                                                       float* __restrict__ T,
                                                       const int* __restrict__ w,
                                                       signed char* __restrict__ w8t) {
    __shared__ float red[4 * 256];
    const int b = blockIdx.x;
    const int tid = threadIdx.x;
    if (b < 2048) {
        // ---- x-path ----
        const int lane = tid & 63, wv = tid >> 6;
        const int fr = lane & 15, fq = lane >> 4;
        const int m0 = (b >> 2) * 16;
        const int ks = b & 3;                    // k-slice [ks*1024, +1024)
        const int bm = m0 >> 8;
        const int g  = (m0 >> 5) & 7;
        const int l5 = (m0 & 16) + fr;           // row & 31
        const int row = m0 + fr;

        v4f acc = {0.f, 0.f, 0.f, 0.f};
#pragma unroll 4
        for (int kt = 0; kt < 8; ++kt) {
            const int k  = ks * 1024 + wv * 256 + kt * 32 + fq * 8;
            const int4* xp = (const int4*)(x + (size_t)row * IN_DIM + k);
            int4 a = xp[0], bb = xp[1];
            const int kk = k >> 6, c = (k >> 4) & 3, j8 = (k >> 3) & 1;
            int2 pk = make_int2(pack4(a.x, a.y, a.z, a.w), pack4(bb.x, bb.y, bb.z, bb.w));
            *(int2*)(x8t + ((size_t)((bm * 64 + kk) * 16 + g * 2 + (c >> 1))) * 1024 +
                     ((c & 1) * 32 + l5) * 16 + j8 * 8) = pk;
            // x fragment: exact int->bf16 ; A fragment: inline f32->bf16 (RNE)
            v8s xa;
            xa[0] = i2bf(a.x);  xa[1] = i2bf(a.y);  xa[2] = i2bf(a.z);  xa[3] = i2bf(a.w);
            xa[4] = i2bf(bb.x); xa[5] = i2bf(bb.y); xa[6] = i2bf(bb.z); xa[7] = i2bf(bb.w);
            const float* ap = la + (size_t)fr * IN_DIM + k;
            float4 af0 = *(const float4*)(ap);
            float4 af1 = *(const float4*)(ap + 4);
            v8s aa;
            aa[0] = f2bf(af0.x); aa[1] = f2bf(af0.y); aa[2] = f2bf(af0.z); aa[3] = f2bf(af0.w);
            aa[4] = f2bf(af1.x); aa[5] = f2bf(af1.y); aa[6] = f2bf(af1.z); aa[7] = f2bf(af1.w);
            acc = __builtin_amdgcn_mfma_f32_16x16x32_bf16(xa, aa, acc, 0, 0, 0);
        }
        *(v4f*)&red[wv * 256 + lane * 4] = acc;
        __syncthreads();

        float s = red[tid] + red[256 + tid] + red[512 + tid] + red[768 + tid];
        const int sl = tid >> 2, j = tid & 3;
        const int r16 = ((sl >> 4) << 2) + j, col = sl & 15;  // C/D 16x16 layout
        atomicAdd(&T[(size_t)(m0 + r16) * 16 + col], s);
    } else {
        // ---- w-path ----
        const int flat = (b - 2048) * 256 + tid;  // 16B slot id, [0, 1M)
        const int l  = flat & 63;
        const int gp = (flat >> 6) & 15;
        const int kk = (flat >> 10) & 63;
        const int bn = flat >> 16;
        const int n = bn * 256 + ((gp >> 1) << 5) + (l & 31);
        const int k = kk * 64 + ((gp & 1) << 5) + ((l >> 5) << 4);
        const int4* p = (const int4*)(w + (size_t)n * IN_DIM + k);
        int4 a = p[0], bb = p[1], c = p[2], d = p[3];
        int4 o;
        o.x = pack4(a.x, a.y, a.z, a.w);
        o.y = pack4(bb.x, bb.y, bb.z, bb.w);
        o.z = pack4(c.x, c.y, c.z, c.w);
        o.w = pack4(d.x, d.y, d.z, d.w);
        *(int4*)(w8t + (size_t)flat * 16) = o;
    }
}

// ---------------- i8 MFMA GEMM: 256x128 block, 4 waves (2Mx2N), 32x32x32 ----------------
// R5-verified optimum of this family (148.6us / 45% MfmaUtil): 2 blocks/CU,
// TWO phases per K-tile each {6 frag ds_reads + 3 staging cp16 + barrier +
// setprio'd 8-MFMA cluster}, publish via counted vmcnt(6) + barrier.
// UNCHANGED from R5/R7 — A/B probe for the R7 session-variance anomaly.
__global__ __launch_bounds__(256, 2) void q8_gemm_kernel(
    const signed char* __restrict__ x8t, const signed char* __restrict__ w8t,
    const float* __restrict__ Tp, const float* __restrict__ lbm,
    const float* __restrict__ bias, const float* __restrict__ xsc,
    const float* __restrict__ wsc, const int* __restrict__ gflag,
    float* __restrict__ out) {
    __shared__ __align__(16) signed char smem[73728];  // 3 x (A 16K | B 8K)

    const int tid  = threadIdx.x;
    const int lane = tid & 63;
    const int wv   = tid >> 6;           // 0..3
    const int wm   = wv >> 1, wn = wv & 1;
    const int b   = blockIdx.x;
    const int xcd = b & 7, rr = b >> 3;   // rr in [0,128)
    const int bm  = xcd * 4 + (rr & 3);   // [0,32)
    const int bn  = rr >> 2;              // [0,32)

    const int lofs = lane * 16;
    const size_t toff = (size_t)tid * 16;
    const signed char* Asrc = x8t + (size_t)bm * (64 * 16 * 1024);
    const signed char* Bsrc = w8t + (size_t)(bn >> 1) * (64 * 16 * 1024) + (bn & 1) * 8192;

    v16i acc[4][2];
    {
        v16i z;
#pragma unroll
        for (int i = 0; i < 16; ++i) z[i] = 0;
#pragma unroll
        for (int mt = 0; mt < 4; ++mt)
#pragma unroll
            for (int nt = 0; nt < 2; ++nt) acc[mt][nt] = z;
    }

    // prologue: tile 0 -> buf0, tile 1 -> buf1 (6 cp16/thread each)
#pragma unroll
    for (int tt = 0; tt < 2; ++tt) {
        const signed char* gA = Asrc + (size_t)tt * 16384 + toff;
        const signed char* gB = Bsrc + (size_t)tt * 16384 + toff;
        signed char* sA = smem + tt * 24576 + (wv << 10);
        signed char* sB = sA + 16384;
        async_cp16(gA,         sA);
        async_cp16(gA + 4096,  sA + 4096);
        async_cp16(gA + 8192,  sA + 8192);
        async_cp16(gA + 12288, sA + 12288);
        async_cp16(gB,         sB);
        async_cp16(gB + 4096,  sB + 4096);
    }
    asm volatile("s_waitcnt vmcnt(6)" ::: "memory");  // tile 0 landed; tile 1 in flight
    __builtin_amdgcn_s_barrier();                     // publish tile 0

    int cur = 0;
    for (int t = 0; t < 64; ++t) {
        const signed char* Ab = smem + cur * 24576;
        const signed char* Bb = Ab + 16384;
        const int sb = (cur == 0) ? 2 : cur - 1;      // (t+2) % 3
        signed char* sA = smem + sb * 24576 + (wv << 10);
        signed char* sB = sA + 16384;
        const signed char* gA = Asrc + (size_t)(t + 2) * 16384 + toff;
        const signed char* gB = Bsrc + (size_t)(t + 2) * 16384 + toff;
        const bool pf = (t < 62);

        v4i a0, a1, a2, a3, b0, b1;

        // ---- phase 0 (s=0): frag reads + half the stage ----
        a0 = *(const v4i*)(Ab + ((wm * 4 + 0) * 2 + 0) * 1024 + lofs);
        a1 = *(const v4i*)(Ab + ((wm * 4 + 1) * 2 + 0) * 1024 + lofs);
        a2 = *(const v4i*)(Ab + ((wm * 4 + 2) * 2 + 0) * 1024 + lofs);
        a3 = *(const v4i*)(Ab + ((wm * 4 + 3) * 2 + 0) * 1024 + lofs);
        b0 = *(const v4i*)(Bb + ((wn * 2 + 0) * 2 + 0) * 1024 + lofs);
        b1 = *(const v4i*)(Bb + ((wn * 2 + 1) * 2 + 0) * 1024 + lofs);
        if (pf) {
            async_cp16(gA,        sA);
            async_cp16(gA + 4096, sA + 4096);
            async_cp16(gB,        sB);
        }
        __builtin_amdgcn_s_barrier();
        __builtin_amdgcn_s_setprio(1);
        acc[0][0] = __builtin_amdgcn_mfma_i32_32x32x32_i8(a0, b0, acc[0][0], 0, 0, 0);
        acc[0][1] = __builtin_amdgcn_mfma_i32_32x32x32_i8(a0, b1, acc[0][1], 0, 0, 0);
        acc[1][0] = __builtin_amdgcn_mfma_i32_32x32x32_i8(a1, b0, acc[1][0], 0, 0, 0);
        acc[1][1] = __builtin_amdgcn_mfma_i32_32x32x32_i8(a1, b1, acc[1][1], 0, 0, 0);
        acc[2][0] = __builtin_amdgcn_mfma_i32_32x32x32_i8(a2, b0, acc[2][0], 0, 0, 0);
        acc[2][1] = __builtin_amdgcn_mfma_i32_32x32x32_i8(a2, b1, acc[2][1], 0, 0, 0);
        acc[3][0] = __builtin_amdgcn_mfma_i32_32x32x32_i8(a3, b0, acc[3][0], 0, 0, 0);
        acc[3][1] = __builtin_amdgcn_mfma_i32_32x32x32_i8(a3, b1, acc[3][1], 0, 0, 0);
        __builtin_amdgcn_s_setprio(0);

        // ---- phase 1 (s=1): frag reads overlap phase-0 MFMA (same barrier region) ----
        a0 = *(const v4i*)(Ab + ((wm * 4 + 0) * 2 + 1) * 1024 + lofs);
        a1 = *(const v4i*)(Ab + ((wm * 4 + 1) * 2 + 1) * 1024 + lofs);
        a2 = *(const v4i*)(Ab + ((wm * 4 + 2) * 2 + 1) * 1024 + lofs);
        a3 = *(const v4i*)(Ab + ((wm * 4 + 3) * 2 + 1) * 1024 + lofs);
        b0 = *(const v4i*)(Bb + ((wn * 2 + 0) * 2 + 1) * 1024 + lofs);
        b1 = *(const v4i*)(Bb + ((wn * 2 + 1) * 2 + 1) * 1024 + lofs);
        if (pf) {
            async_cp16(gA + 8192,  sA + 8192);
            async_cp16(gA + 12288, sA + 12288);
            async_cp16(gB + 4096,  sB + 4096);
        }
        __builtin_amdgcn_s_barrier();
        __builtin_amdgcn_s_setprio(1);
        acc[0][0] = __builtin_amdgcn_mfma_i32_32x32x32_i8(a0, b0, acc[0][0], 0, 0, 0);
        acc[0][1] = __builtin_amdgcn_mfma_i32_32x32x32_i8(a0, b1, acc[0][1], 0, 0, 0);
        acc[1][0] = __builtin_amdgcn_mfma_i32_32x32x32_i8(a1, b0, acc[1][0], 0, 0, 0);
        acc[1][1] = __builtin_amdgcn_mfma_i32_32x32x32_i8(a1, b1, acc[1][1], 0, 0, 0);
        acc[2][0] = __builtin_amdgcn_mfma_i32_32x32x32_i8(a2, b0, acc[2][0], 0, 0, 0);
        acc[2][1] = __builtin_amdgcn_mfma_i32_32x32x32_i8(a2, b1, acc[2][1], 0, 0, 0);
        acc[3][0] = __builtin_amdgcn_mfma_i32_32x32x32_i8(a3, b0, acc[3][0], 0, 0, 0);
        acc[3][1] = __builtin_amdgcn_mfma_i32_32x32x32_i8(a3, b1, acc[3][1], 0, 0, 0);
        __builtin_amdgcn_s_setprio(0);

        // publish tile t+1: retire its 6 loads; tile t+2's 6 stay in flight
        if (pf) {
            asm volatile("s_waitcnt vmcnt(6)" ::: "memory");
        } else if (t == 62) {
            asm volatile("s_waitcnt vmcnt(0)" ::: "memory");
        }
        if (t < 63) __builtin_amdgcn_s_barrier();
        cur = (cur == 2) ? 0 : cur + 1;
    }

    // ---------------- epilogue: all operands straight from global (no LDS) ----------------
    const int mbase = bm * 256 + wm * 128;
    const int nbase = bn * 128 + wn * 64;
    const int l31 = lane & 31, lh = lane >> 5;
    const bool dg = (*gflag) != 0;

    v8s tf[4], bf[2];
#pragma unroll
    for (int mt = 0; mt < 4; ++mt) {
        const float* t0 = Tp + (size_t)(mbase + mt * 32 + l31) * 16 + lh * 8;
        v8s v;
#pragma unroll
        for (int j = 0; j < 8; ++j) v[j] = f2bf(t0[j]);
        tf[mt] = v;
    }
#pragma unroll
    for (int nt = 0; nt < 2; ++nt) {
        const float* bp = lbm + (size_t)(nbase + nt * 32 + l31) * 16 + lh * 8;
        v8s v;
#pragma unroll
        for (int j = 0; j < 8; ++j) v[j] = f2bf(bp[j]);
        bf[nt] = v;
    }
    float wsa[2], bba[2];
#pragma unroll
    for (int nt = 0; nt < 2; ++nt) {
        const int col = nbase + nt * 32 + l31;
        wsa[nt] = wsc[col];
        bba[nt] = bias[col];
    }

#pragma unroll
    for (int mt = 0; mt < 4; ++mt) {
        const int rowb = mbase + mt * 32 + lh * 4;
        float4 xs0 = *(const float4*)(xsc + rowb);
        float4 xs1 = *(const float4*)(xsc + rowb + 8);
        float4 xs2 = *(const float4*)(xsc + rowb + 16);
        float4 xs3 = *(const float4*)(xsc + rowb + 24);
        float xsv[16] = {xs0.x, xs0.y, xs0.z, xs0.w, xs1.x, xs1.y, xs1.z, xs1.w,
                         xs2.x, xs2.y, xs2.z, xs2.w, xs3.x, xs3.y, xs3.z, xs3.w};
#pragma unroll
        for (int nt = 0; nt < 2; ++nt) {
            v16f fa;
#pragma unroll
            for (int i = 0; i < 16; ++i) fa[i] = (float)acc[mt][nt][i] * wsa[nt];
            fa = __builtin_amdgcn_mfma_f32_32x32x16_bf16(tf[mt], bf[nt], fa, 0, 0, 0);
            const int col = nbase + nt * 32 + l31;
#pragma unroll
            for (int r = 0; r < 16; ++r) {
                float u = fmaf(xsv[r], fa[r], bba[nt]);
                if (dg) u = gelu_tanh(u);
                out[(size_t)(rowb + (r & 3) + 8 * (r >> 2)) * OUT_DIM + col] = u;
            }
        }
    }
}

extern "C" void kernel_launch(void* const* d_in, const int* in_sizes, int n_in,
                              void* d_out, int out_size, void* d_ws, size_t ws_size,
                              hipStream_t stream) {
    const int*   x     = (const int*)d_in[0];
    const int*   wt    = (const int*)d_in[1];
    const float* bias  = (const float*)d_in[2];
    const float* xsc   = (const float*)d_in[3];
    const float* wsc   = (const float*)d_in[4];
    const float* la    = (const float*)d_in[5];
    const float* lb    = (const float*)d_in[6];
    const int*   gflag = (const int*)d_in[7];
    float* out = (float*)d_out;

    signed char* x8t = (signed char*)d_ws;
    signed char* w8t = x8t + (size_t)M_DIM * IN_DIM;
    float* T = (float*)(w8t + (size_t)OUT_DIM * IN_DIM);

    zero_t_kernel<<<64, 256, 0, stream>>>(T);
    pack_all_kernel<<<2048 + 4096, 256, 0, stream>>>(x, la, x8t, T, wt, w8t);
    q8_gemm_kernel<<<(M_DIM / 256) * (OUT_DIM / 128), 256, 0, stream>>>(
        x8t, w8t, T, lb, bias, xsc, wsc, gflag, out);
}

// Round 9
// 413.638 us; speedup vs baseline: 1.0123x; 1.0123x over previous
//
#include <hip/hip_runtime.h>

#define M_DIM 8192
#define IN_DIM 4096
#define OUT_DIM 4096

typedef int   v4i  __attribute__((ext_vector_type(4)));
typedef int   v16i __attribute__((ext_vector_type(16)));
typedef short v8s  __attribute__((ext_vector_type(8)));
typedef float v4f  __attribute__((ext_vector_type(4)));
typedef float v16f __attribute__((ext_vector_type(16)));

static __device__ __forceinline__ int pack4(int a, int b, int c, int d) {
    return (a & 255) | ((b & 255) << 8) | ((c & 255) << 16) | ((d & 255) << 24);
}

static __device__ __forceinline__ short f2bf(float f) {  // RNE
    unsigned u = __float_as_uint(f);
    u = (u + 0x7FFFu + ((u >> 16) & 1u)) >> 16;
    return (short)u;
}

static __device__ __forceinline__ short i2bf(int v) {  // exact for |v| <= 128
    float f = (float)v;
    return (short)(__float_as_uint(f) >> 16);
}

static __device__ __forceinline__ float gelu_tanh(float u) {
    float u2 = u * u;
    float p  = fmaf(u2, 0.0356774081f, 0.7978845608f);
    float v  = u * p;
    float e  = __builtin_amdgcn_exp2f(v * 2.8853900818f);
    return u - u * __builtin_amdgcn_rcpf(e + 1.0f);
}

static __device__ __forceinline__ void async_cp16(const signed char* g, signed char* l) {
    __builtin_amdgcn_global_load_lds((const __attribute__((address_space(1))) void*)g,
                                     (__attribute__((address_space(3))) void*)l, 16, 0, 0);
}

// Tiled operand layout (shared by pack paths and GEMM staging):
//   buf[((tile*64 + kk)*16 + gp)*1024 + lane*16 + j] = src[row][k]
//   row = tile*256 + (gp>>1)*32 + (lane&31)
//   k   = kk*64 + (gp&1)*32 + (lane>>5)*16 + j ,  j in [0,16)

// ---------------- lora_a fp32 -> bf16 ; also zero T for pack atomics ----------------
// Pre-converting a16 keeps the x-path's A-fragment a single 16B load (R8's
// inline f2bf added ~32 VALU/iter on the hot loop and measured ~25us worse).
__global__ __launch_bounds__(256) void pack_a_kernel(const float* __restrict__ la,
                                                     short* __restrict__ a16,
                                                     float* __restrict__ T) {
    const int flat = blockIdx.x * 256 + threadIdx.x;  // 16384 threads
    size_t i = (size_t)flat * 4;                       // 65536 = R*IN elems
    float4 a = *(const float4*)(la + i);
    short4 o;
    o.x = f2bf(a.x); o.y = f2bf(a.y); o.z = f2bf(a.z); o.w = f2bf(a.w);
    *(short4*)(a16 + i) = o;
    // zero T: 16384 threads x 8 floats = 131072 = M*R
    float4 z = {0.f, 0.f, 0.f, 0.f};
    float4* tz = (float4*)(T + (size_t)flat * 8);
    tz[0] = z; tz[1] = z;
}

// ---------------- device bodies shared by fused / fallback kernels ----------------
static __device__ __forceinline__ void do_pack_w(int flat, const int* __restrict__ w,
                                                 signed char* __restrict__ w8t) {
    const int l  = flat & 63;
    const int gp = (flat >> 6) & 15;
    const int kk = (flat >> 10) & 63;
    const int bn = flat >> 16;
    const int n = bn * 256 + ((gp >> 1) << 5) + (l & 31);
    const int k = kk * 64 + ((gp & 1) << 5) + ((l >> 5) << 4);
    const int4* p = (const int4*)(w + (size_t)n * IN_DIM + k);
    int4 a = p[0], b = p[1], c = p[2], d = p[3];
    int4 o;
    o.x = pack4(a.x, a.y, a.z, a.w);
    o.y = pack4(b.x, b.y, b.z, b.w);
    o.z = pack4(c.x, c.y, c.z, c.w);
    o.w = pack4(d.x, d.y, d.z, d.w);
    *(int4*)(w8t + (size_t)flat * 16) = o;
}

// x int32 -> int8 tiled layout AND T[m][r] += partial lora. 8-way K-split:
// block = 16 rows x 512-k slice; per wave 128 k (4 MFMA iters). atomicAdd into T.
static __device__ __forceinline__ void do_pack_x(int blk, int tid, float* red,
                                                 const int* __restrict__ x,
                                                 const short* __restrict__ a16,
                                                 signed char* __restrict__ x8t,
                                                 float* __restrict__ T) {
    const int lane = tid & 63, wv = tid >> 6;
    const int fr = lane & 15, fq = lane >> 4;
    const int m0 = (blk >> 3) * 16;
    const int ks = blk & 7;                  // k-slice [ks*512, ks*512+512)
    const int bm = m0 >> 8;
    const int g  = (m0 >> 5) & 7;
    const int l5 = (m0 & 16) + fr;           // row & 31
    const int row = m0 + fr;

    v4f acc = {0.f, 0.f, 0.f, 0.f};
#pragma unroll 4
    for (int kt = 0; kt < 4; ++kt) {
        const int k  = ks * 512 + wv * 128 + kt * 32 + fq * 8;
        const int4* xp = (const int4*)(x + (size_t)row * IN_DIM + k);
        int4 a = xp[0], b = xp[1];
        const int kk = k >> 6, c = (k >> 4) & 3, j8 = (k >> 3) & 1;
        int2 pk = make_int2(pack4(a.x, a.y, a.z, a.w), pack4(b.x, b.y, b.z, b.w));
        *(int2*)(x8t + ((size_t)((bm * 64 + kk) * 16 + g * 2 + (c >> 1))) * 1024 +
                 ((c & 1) * 32 + l5) * 16 + j8 * 8) = pk;
        v8s xa;
        xa[0] = i2bf(a.x); xa[1] = i2bf(a.y); xa[2] = i2bf(a.z); xa[3] = i2bf(a.w);
        xa[4] = i2bf(b.x); xa[5] = i2bf(b.y); xa[6] = i2bf(b.z); xa[7] = i2bf(b.w);
        v8s aa = *(const v8s*)(a16 + (size_t)fr * IN_DIM + k);
        acc = __builtin_amdgcn_mfma_f32_16x16x32_bf16(xa, aa, acc, 0, 0, 0);
    }
    *(v4f*)&red[wv * 256 + lane * 4] = acc;
    __syncthreads();

    float s = red[tid] + red[256 + tid] + red[512 + tid] + red[768 + tid];
    const int sl = tid >> 2, j = tid & 3;
    const int r16 = ((sl >> 4) << 2) + j, col = sl & 15;  // C/D 16x16 layout
    atomicAdd(&T[(size_t)(m0 + r16) * 16 + col], s);
}

// ---------------- fused pack (a16 NOT aliased): x-path + w-path in one launch ----------------
// blocks [0,4096): x-pack+lora (8-way K-split) ; [4096,8192): w-pack.
// Independent work; w-path's BW-bound blocks fill x-path's latency stalls.
__global__ __launch_bounds__(256) void pack_xw_kernel(const int* __restrict__ x,
                                                      const short* __restrict__ a16,
                                                      signed char* __restrict__ x8t,
                                                      float* __restrict__ T,
                                                      const int* __restrict__ w,
                                                      signed char* __restrict__ w8t) {
    __shared__ float red[4 * 256];
    const int b = blockIdx.x;
    if (b < 4096) {
        do_pack_x(b, threadIdx.x, red, x, a16, x8t, T);
    } else {
        do_pack_w((b - 4096) * 256 + threadIdx.x, w, w8t);
    }
}

// ---------------- fallback kernels (a16 aliased into w8t head; serial chain) ----------------
__global__ __launch_bounds__(256) void pack_w_kernel(const int* __restrict__ w,
                                                     signed char* __restrict__ w8t) {
    do_pack_w(blockIdx.x * 256 + threadIdx.x, w, w8t);
}

__global__ __launch_bounds__(256) void pack_x_lora_kernel(const int* __restrict__ x,
                                                          const short* __restrict__ a16,
                                                          signed char* __restrict__ x8t,
                                                          float* __restrict__ T) {
    __shared__ float red[4 * 256];
    do_pack_x(blockIdx.x, threadIdx.x, red, x, a16, x8t, T);
}

// ---------------- i8 MFMA GEMM: 256x128 block, 4 waves (2Mx2N), 32x32x32 ----------------
// R5-verified optimum of this family (148.6-149us / 44-45% MfmaUtil, reproduced
// R8): 2 blocks/CU, TWO phases per K-tile each {6 frag ds_reads + 3 staging cp16
// + barrier + setprio'd 8-MFMA cluster}, publish via counted vmcnt(6) + barrier.
// UNCHANGED — serves as the cross-round A/B control.
__global__ __launch_bounds__(256, 2) void q8_gemm_kernel(
    const signed char* __restrict__ x8t, const signed char* __restrict__ w8t,
    const float* __restrict__ Tp, const float* __restrict__ lbm,
    const float* __restrict__ bias, const float* __restrict__ xsc,
    const float* __restrict__ wsc, const int* __restrict__ gflag,
    float* __restrict__ out) {
    __shared__ __align__(16) signed char smem[73728];  // 3 x (A 16K | B 8K)

    const int tid  = threadIdx.x;
    const int lane = tid & 63;
    const int wv   = tid >> 6;           // 0..3
    const int wm   = wv >> 1, wn = wv & 1;
    const int b   = blockIdx.x;
    const int xcd = b & 7, rr = b >> 3;   // rr in [0,128)
    const int bm  = xcd * 4 + (rr & 3);   // [0,32)
    const int bn  = rr >> 2;              // [0,32)

    const int lofs = lane * 16;
    const size_t toff = (size_t)tid * 16;
    const signed char* Asrc = x8t + (size_t)bm * (64 * 16 * 1024);
    const signed char* Bsrc = w8t + (size_t)(bn >> 1) * (64 * 16 * 1024) + (bn & 1) * 8192;

    v16i acc[4][2];
    {
        v16i z;
#pragma unroll
        for (int i = 0; i < 16; ++i) z[i] = 0;
#pragma unroll
        for (int mt = 0; mt < 4; ++mt)
#pragma unroll
            for (int nt = 0; nt < 2; ++nt) acc[mt][nt] = z;
    }

    // prologue: tile 0 -> buf0, tile 1 -> buf1 (6 cp16/thread each)
#pragma unroll
    for (int tt = 0; tt < 2; ++tt) {
        const signed char* gA = Asrc + (size_t)tt * 16384 + toff;
        const signed char* gB = Bsrc + (size_t)tt * 16384 + toff;
        signed char* sA = smem + tt * 24576 + (wv << 10);
        signed char* sB = sA + 16384;
        async_cp16(gA,         sA);
        async_cp16(gA + 4096,  sA + 4096);
        async_cp16(gA + 8192,  sA + 8192);
        async_cp16(gA + 12288, sA + 12288);
        async_cp16(gB,         sB);
        async_cp16(gB + 4096,  sB + 4096);
    }
    asm volatile("s_waitcnt vmcnt(6)" ::: "memory");  // tile 0 landed; tile 1 in flight
    __builtin_amdgcn_s_barrier();                     // publish tile 0

    int cur = 0;
    for (int t = 0; t < 64; ++t) {
        const signed char* Ab = smem + cur * 24576;
        const signed char* Bb = Ab + 16384;
        const int sb = (cur == 0) ? 2 : cur - 1;      // (t+2) % 3
        signed char* sA = smem + sb * 24576 + (wv << 10);
        signed char* sB = sA + 16384;
        const signed char* gA = Asrc + (size_t)(t + 2) * 16384 + toff;
        const signed char* gB = Bsrc + (size_t)(t + 2) * 16384 + toff;
        const bool pf = (t < 62);

        v4i a0, a1, a2, a3, b0, b1;

        // ---- phase 0 (s=0): frag reads + half the stage ----
        a0 = *(const v4i*)(Ab + ((wm * 4 + 0) * 2 + 0) * 1024 + lofs);
        a1 = *(const v4i*)(Ab + ((wm * 4 + 1) * 2 + 0) * 1024 + lofs);
        a2 = *(const v4i*)(Ab + ((wm * 4 + 2) * 2 + 0) * 1024 + lofs);
        a3 = *(const v4i*)(Ab + ((wm * 4 + 3) * 2 + 0) * 1024 + lofs);
        b0 = *(const v4i*)(Bb + ((wn * 2 + 0) * 2 + 0) * 1024 + lofs);
        b1 = *(const v4i*)(Bb + ((wn * 2 + 1) * 2 + 0) * 1024 + lofs);
        if (pf) {
            async_cp16(gA,        sA);
            async_cp16(gA + 4096, sA + 4096);
            async_cp16(gB,        sB);
        }
        __builtin_amdgcn_s_barrier();
        __builtin_amdgcn_s_setprio(1);
        acc[0][0] = __builtin_amdgcn_mfma_i32_32x32x32_i8(a0, b0, acc[0][0], 0, 0, 0);
        acc[0][1] = __builtin_amdgcn_mfma_i32_32x32x32_i8(a0, b1, acc[0][1], 0, 0, 0);
        acc[1][0] = __builtin_amdgcn_mfma_i32_32x32x32_i8(a1, b0, acc[1][0], 0, 0, 0);
        acc[1][1] = __builtin_amdgcn_mfma_i32_32x32x32_i8(a1, b1, acc[1][1], 0, 0, 0);
        acc[2][0] = __builtin_amdgcn_mfma_i32_32x32x32_i8(a2, b0, acc[2][0], 0, 0, 0);
        acc[2][1] = __builtin_amdgcn_mfma_i32_32x32x32_i8(a2, b1, acc[2][1], 0, 0, 0);
        acc[3][0] = __builtin_amdgcn_mfma_i32_32x32x32_i8(a3, b0, acc[3][0], 0, 0, 0);
        acc[3][1] = __builtin_amdgcn_mfma_i32_32x32x32_i8(a3, b1, acc[3][1], 0, 0, 0);
        __builtin_amdgcn_s_setprio(0);

        // ---- phase 1 (s=1): frag reads overlap phase-0 MFMA (same barrier region) ----
        a0 = *(const v4i*)(Ab + ((wm * 4 + 0) * 2 + 1) * 1024 + lofs);
        a1 = *(const v4i*)(Ab + ((wm * 4 + 1) * 2 + 1) * 1024 + lofs);
        a2 = *(const v4i*)(Ab + ((wm * 4 + 2) * 2 + 1) * 1024 + lofs);
        a3 = *(const v4i*)(Ab + ((wm * 4 + 3) * 2 + 1) * 1024 + lofs);
        b0 = *(const v4i*)(Bb + ((wn * 2 + 0) * 2 + 1) * 1024 + lofs);
        b1 = *(const v4i*)(Bb + ((wn * 2 + 1) * 2 + 1) * 1024 + lofs);
        if (pf) {
            async_cp16(gA + 8192,  sA + 8192);
            async_cp16(gA + 12288, sA + 12288);
            async_cp16(gB + 4096,  sB + 4096);
        }
        __builtin_amdgcn_s_barrier();
        __builtin_amdgcn_s_setprio(1);
        acc[0][0] = __builtin_amdgcn_mfma_i32_32x32x32_i8(a0, b0, acc[0][0], 0, 0, 0);
        acc[0][1] = __builtin_amdgcn_mfma_i32_32x32x32_i8(a0, b1, acc[0][1], 0, 0, 0);
        acc[1][0] = __builtin_amdgcn_mfma_i32_32x32x32_i8(a1, b0, acc[1][0], 0, 0, 0);
        acc[1][1] = __builtin_amdgcn_mfma_i32_32x32x32_i8(a1, b1, acc[1][1], 0, 0, 0);
        acc[2][0] = __builtin_amdgcn_mfma_i32_32x32x32_i8(a2, b0, acc[2][0], 0, 0, 0);
        acc[2][1] = __builtin_amdgcn_mfma_i32_32x32x32_i8(a2, b1, acc[2][1], 0, 0, 0);
        acc[3][0] = __builtin_amdgcn_mfma_i32_32x32x32_i8(a3, b0, acc[3][0], 0, 0, 0);
        acc[3][1] = __builtin_amdgcn_mfma_i32_32x32x32_i8(a3, b1, acc[3][1], 0, 0, 0);
        __builtin_amdgcn_s_setprio(0);

        // publish tile t+1: retire its 6 loads; tile t+2's 6 stay in flight
        if (pf) {
            asm volatile("s_waitcnt vmcnt(6)" ::: "memory");
        } else if (t == 62) {
            asm volatile("s_waitcnt vmcnt(0)" ::: "memory");
        }
        if (t < 63) __builtin_amdgcn_s_barrier();
        cur = (cur == 2) ? 0 : cur + 1;
    }

    // ---------------- epilogue: all operands straight from global (no LDS) ----------------
    const int mbase = bm * 256 + wm * 128;
    const int nbase = bn * 128 + wn * 64;
    const int l31 = lane & 31, lh = lane >> 5;
    const bool dg = (*gflag) != 0;

    v8s tf[4], bf[2];
#pragma unroll
    for (int mt = 0; mt < 4; ++mt) {
        const float* t0 = Tp + (size_t)(mbase + mt * 32 + l31) * 16 + lh * 8;
        v8s v;
#pragma unroll
        for (int j = 0; j < 8; ++j) v[j] = f2bf(t0[j]);
        tf[mt] = v;
    }
#pragma unroll
    for (int nt = 0; nt < 2; ++nt) {
        const float* bp = lbm + (size_t)(nbase + nt * 32 + l31) * 16 + lh * 8;
        v8s v;
#pragma unroll
        for (int j = 0; j < 8; ++j) v[j] = f2bf(bp[j]);
        bf[nt] = v;
    }
    float wsa[2], bba[2];
#pragma unroll
    for (int nt = 0; nt < 2; ++nt) {
        const int col = nbase + nt * 32 + l31;
        wsa[nt] = wsc[col];
        bba[nt] = bias[col];
    }

#pragma unroll
    for (int mt = 0; mt < 4; ++mt) {
        const int rowb = mbase + mt * 32 + lh * 4;
        float4 xs0 = *(const float4*)(xsc + rowb);
        float4 xs1 = *(const float4*)(xsc + rowb + 8);
        float4 xs2 = *(const float4*)(xsc + rowb + 16);
        float4 xs3 = *(const float4*)(xsc + rowb + 24);
        float xsv[16] = {xs0.x, xs0.y, xs0.z, xs0.w, xs1.x, xs1.y, xs1.z, xs1.w,
                         xs2.x, xs2.y, xs2.z, xs2.w, xs3.x, xs3.y, xs3.z, xs3.w};
#pragma unroll
        for (int nt = 0; nt < 2; ++nt) {
            v16f fa;
#pragma unroll
            for (int i = 0; i < 16; ++i) fa[i] = (float)acc[mt][nt][i] * wsa[nt];
            fa = __builtin_amdgcn_mfma_f32_32x32x16_bf16(tf[mt], bf[nt], fa, 0, 0, 0);
            const int col = nbase + nt * 32 + l31;
#pragma unroll
            for (int r = 0; r < 16; ++r) {
                float u = fmaf(xsv[r], fa[r], bba[nt]);
                if (dg) u = gelu_tanh(u);
                out[(size_t)(rowb + (r & 3) + 8 * (r >> 2)) * OUT_DIM + col] = u;
            }
        }
    }
}

extern "C" void kernel_launch(void* const* d_in, const int* in_sizes, int n_in,
                              void* d_out, int out_size, void* d_ws, size_t ws_size,
                              hipStream_t stream) {
    const int*   x     = (const int*)d_in[0];
    const int*   wt    = (const int*)d_in[1];
    const float* bias  = (const float*)d_in[2];
    const float* xsc   = (const float*)d_in[3];
    const float* wsc   = (const float*)d_in[4];
    const float* la    = (const float*)d_in[5];
    const float* lb    = (const float*)d_in[6];
    const int*   gflag = (const int*)d_in[7];
    float* out = (float*)d_out;

    signed char* x8t = (signed char*)d_ws;
    signed char* w8t = x8t + (size_t)M_DIM * IN_DIM;
    float* T = (float*)(w8t + (size_t)OUT_DIM * IN_DIM);

    const size_t base = (size_t)M_DIM * IN_DIM + (size_t)OUT_DIM * IN_DIM +
                        (size_t)M_DIM * 16 * 4;
    const size_t a16_bytes = (size_t)16 * IN_DIM * 2;

    if (ws_size >= base + a16_bytes) {
        // a16 lives after T -> x-pack and w-pack are independent; fuse them.
        short* a16 = (short*)((char*)d_ws + base);
        pack_a_kernel<<<64, 256, 0, stream>>>(la, a16, T);
        pack_xw_kernel<<<8192, 256, 0, stream>>>(x, a16, x8t, T, wt, w8t);
    } else {
        // tight workspace: alias a16 into w8t head; keep the serial chain
        short* a16 = (short*)w8t;
        pack_a_kernel<<<64, 256, 0, stream>>>(la, a16, T);
        pack_x_lora_kernel<<<(M_DIM / 16) * 8, 256, 0, stream>>>(x, a16, x8t, T);
        pack_w_kernel<<<(size_t)OUT_DIM * IN_DIM / (16 * 256), 256, 0, stream>>>(wt, w8t);
    }
    q8_gemm_kernel<<<(M_DIM / 256) * (OUT_DIM / 128), 256, 0, stream>>>(
        x8t, w8t, T, lb, bias, xsc, wsc, gflag, out);
}